// Round 12
// baseline (247.129 us; speedup 1.0000x reference)
//
#include <hip/hip_runtime.h>
#include <math.h>

#define B_ 16
#define L_ 1024
#define M_TOT (B_*L_)   // 16384

typedef __attribute__((ext_vector_type(8))) short short8v;  // 8 bf16 (4 VGPRs)
typedef __attribute__((ext_vector_type(4))) float f32x4;

__device__ __forceinline__ float wave_reduce_sum(float v) {
#pragma unroll
  for (int o = 32; o >= 1; o >>= 1) v += __shfl_xor(v, o, 64);
  return v;
}

__device__ __forceinline__ unsigned short f2bf(float f) {
  union { float f; unsigned u; } v; v.f = f;
  unsigned r = v.u + 0x7FFFu + ((v.u >> 16) & 1u);
  return (unsigned short)(r >> 16);
}

// ---------------- fused weight pack: fp32 [nmat][K][N] -> MFMA B-frag bf16 ----
__global__ __launch_bounds__(256) void pack_all_kernel(
    const float* __restrict__ s0, const float* __restrict__ s1,
    const float* __restrict__ s2, const float* __restrict__ s3,
    const float* __restrict__ s4, const float* __restrict__ s5,
    const float* __restrict__ s6, unsigned short* __restrict__ wpk)
{
  int idx = blockIdx.x*256 + (int)threadIdx.x;
  const float* src; unsigned short* dst; int K, N;
  if      (idx <  4096) { src=s0; dst=wpk;          K=64;  N=64;  }
  else if (idx <  6144) { src=s1; dst=wpk+32768;    K=64;  N=128; idx-=4096; }
  else if (idx <  8192) { src=s2; dst=wpk+49152;    K=128; N=64;  idx-=6144; }
  else if (idx < 24576) { src=s3; dst=wpk+65536;    K=128; N=128; idx-=8192; }
  else if (idx < 32768) { src=s4; dst=wpk+196608;   K=128; N=256; idx-=24576; }
  else if (idx < 40960) { src=s5; dst=wpk+262144;   K=256; N=128; idx-=32768; }
  else if (idx < 41984) { src=s6; dst=wpk+327680;   K=64;  N=128; idx-=40960; }
  else return;
  const int l = idx & 63;
  int f = idx >> 6;
  const int ntn = N >> 4;
  const int nt = f % ntn; f /= ntn;
  const int ktn = K >> 5;
  const int kt = f % ktn;
  const int m  = f / ktn;
  const float* s = src + (size_t)m*K*N + (size_t)(kt*32 + ((l>>4)<<3))*N + nt*16 + (l&15);
  unsigned pw[4];
#pragma unroll
  for (int jj = 0; jj < 4; ++jj)
    pw[jj] = (unsigned)f2bf(s[(size_t)(2*jj)*N]) | ((unsigned)f2bf(s[(size_t)(2*jj+1)*N]) << 16);
  uint4 u; u.x = pw[0]; u.y = pw[1]; u.z = pw[2]; u.w = pw[3];
  *reinterpret_cast<uint4*>(dst + (size_t)idx*8) = u;
}

// ---------------- MFMA GEMM: C = act(A[M,K] @ W[K,PN per part] + bias) --------
template<int K, int PN, int NPARTS, bool RELU, bool GATED, bool WF32, bool WBF,
         int SPART = -1, bool SEMB0 = false>
__global__ __launch_bounds__(256) void mgemm_kernel(
    const unsigned short* __restrict__ Abf,
    const unsigned short* __restrict__ Wpk,
    const float* __restrict__ bias,
    float* __restrict__ C, unsigned short* __restrict__ Cbf,
    const int* __restrict__ nseg, float* __restrict__ semb0)
{
  constexpr int NOUT = NPARTS*PN;
  constexpr int KT = K/32;
  constexpr int NTP = PN/16;
  constexpr int CPP = PN/64;
  const int row0 = blockIdx.x * 64;
  if (GATED) { const int b = row0 >> 10; if ((row0 & (L_-1)) >= nseg[b]) return; }
  const int ct = blockIdx.y;
  const int part = ct / CPP;
  const int nt0  = (ct % CPP) * 4;
  const int wv = (int)threadIdx.x >> 6;
  const int ln = (int)threadIdx.x & 63;
  const int rbase = row0 + wv*16;
  const unsigned short* aptr = Abf + (size_t)(rbase + (ln & 15))*K + ((ln >> 4) << 3);
  const unsigned short* bptr = Wpk + ((size_t)part*KT*NTP + nt0)*512 + (size_t)ln*8;
  f32x4 acc0 = {0.f,0.f,0.f,0.f}, acc1 = {0.f,0.f,0.f,0.f};
  f32x4 acc2 = {0.f,0.f,0.f,0.f}, acc3 = {0.f,0.f,0.f,0.f};
#pragma unroll
  for (int kt = 0; kt < KT; ++kt) {
    short8v a = *reinterpret_cast<const short8v*>(aptr + kt*32);
    const unsigned short* bk = bptr + (size_t)kt*NTP*512;
    short8v b0 = *reinterpret_cast<const short8v*>(bk);
    short8v b1 = *reinterpret_cast<const short8v*>(bk + 512);
    short8v b2 = *reinterpret_cast<const short8v*>(bk + 1024);
    short8v b3 = *reinterpret_cast<const short8v*>(bk + 1536);
    acc0 = __builtin_amdgcn_mfma_f32_16x16x32_bf16(a, b0, acc0, 0, 0, 0);
    acc1 = __builtin_amdgcn_mfma_f32_16x16x32_bf16(a, b1, acc1, 0, 0, 0);
    acc2 = __builtin_amdgcn_mfma_f32_16x16x32_bf16(a, b2, acc2, 0, 0, 0);
    acc3 = __builtin_amdgcn_mfma_f32_16x16x32_bf16(a, b3, acc3, 0, 0, 0);
  }
  const int colb = part*PN + nt0*16 + (ln & 15);
  const int rowe = rbase + ((ln >> 4) << 2);
  f32x4 av[4] = {acc0, acc1, acc2, acc3};
#pragma unroll
  for (int i = 0; i < 4; ++i) {
    const int col = colb + i*16;
    const float bs = bias[col];
#pragma unroll
    for (int r = 0; r < 4; ++r) {
      float v = av[i][r] + bs;
      if (SPART >= 0) { if (part == SPART) v *= 0.25506972533f; }  // 1/sqrt(32)*log2e
      if (RELU) v = fmaxf(v, 0.f);
      const int row = rowe + r;
      if (WF32) C[(size_t)row*NOUT + col] = v;
      if (WBF)  Cbf[(size_t)row*NOUT + col] = f2bf(v);
      if (SEMB0) { if ((row & (L_-1)) == 0) semb0[(row >> 10)*NOUT + col] = v; }
    }
  }
}

// ---------------- fused QKV GEMM -> attention fragment layouts ----------------
__global__ __launch_bounds__(256) void mgemm_qkvfrag_kernel(
    const unsigned short* __restrict__ Abf,
    const unsigned short* __restrict__ Wpk,
    const float* __restrict__ bias,
    unsigned short* __restrict__ qbf,
    unsigned short* __restrict__ kfrag,
    unsigned short* __restrict__ vfrag,
    const int* __restrict__ nseg)
{
  constexpr int K = 128, PN = 128, KT = 4, NTP = 8;
  const int row0 = blockIdx.x * 64;
  const int bb = row0 >> 10;
  if ((row0 & (L_-1)) >= nseg[bb]) return;
  const int ct = blockIdx.y;          // 0..5
  const int part = ct >> 1;
  const int nt0 = (ct & 1) * 4;
  const int wv = (int)threadIdx.x >> 6;
  const int ln = (int)threadIdx.x & 63;
  const int qc = ln & 15;
  const int rbase = row0 + wv*16;
  const unsigned short* aptr = Abf + (size_t)(rbase + qc)*K + ((ln >> 4) << 3);
  const unsigned short* bptr = Wpk + ((size_t)part*KT*NTP + nt0)*512 + (size_t)ln*8;
  f32x4 acc[4];
#pragma unroll
  for (int i = 0; i < 4; ++i) acc[i] = f32x4{0.f,0.f,0.f,0.f};
#pragma unroll
  for (int kt = 0; kt < KT; ++kt) {
    short8v a = *reinterpret_cast<const short8v*>(aptr + kt*32);
    const unsigned short* bk = bptr + (size_t)kt*NTP*512;
#pragma unroll
    for (int i = 0; i < 4; ++i)
      acc[i] = __builtin_amdgcn_mfma_f32_16x16x32_bf16(
          a, *reinterpret_cast<const short8v*>(bk + i*512), acc[i], 0, 0, 0);
  }
  const int rowe = rbase + ((ln >> 4) << 2);
#pragma unroll
  for (int i = 0; i < 4; ++i) {
    const int cl = (nt0 + i)*16 + qc;
    const int h = cl >> 5, dh = cl & 31;
    const float bs = bias[part*PN + cl];
#pragma unroll
    for (int r = 0; r < 4; ++r) {
      float v = acc[i][r] + bs;
      const int row = rowe + r;
      const int key = row & (L_-1);
      if (part == 0) {
        v *= 0.25506972533f;  // 1/sqrt(32)*log2e
        qbf[(size_t)row*128 + cl] = f2bf(v);
      } else if (part == 1) {
        const size_t idx = (((size_t)((bb*4 + h)*32 + (key>>5))*2 + ((key>>4)&1))*64
                            + ((dh>>3)*16 + (key&15)))*8 + (dh&7);
        kfrag[idx] = f2bf(v);
      } else {
        const int kk = key & 31;
        const size_t idx = (((size_t)((bb*4 + h)*32 + (key>>5))*2 + (dh>>4))*64
                            + (((kk&15)>>2)*16 + (dh&15)))*8 + ((kk>>4)*4 + (kk&3));
        vfrag[idx] = f2bf(v);
      }
    }
  }
}

// ---------------- MFMA GEMM + residual + LayerNorm fused (D=64 rows) ----------
template<int K>
__global__ __launch_bounds__(256) void mgemm_ln64_kernel(
    const unsigned short* __restrict__ Abf,
    const unsigned short* __restrict__ Wpk,
    const float* __restrict__ bias,
    float* __restrict__ x,                 // residual in, fp32 out (in-place)
    const float* __restrict__ gam, const float* __restrict__ bet,
    unsigned short* __restrict__ xbf)
{
  constexpr int KT = K/32;
  const int row0 = blockIdx.x * 64;
  const int wv = (int)threadIdx.x >> 6;
  const int ln = (int)threadIdx.x & 63;
  const int rbase = row0 + wv*16;
  const unsigned short* aptr = Abf + (size_t)(rbase + (ln & 15))*K + ((ln >> 4) << 3);
  const unsigned short* bptr = Wpk + (size_t)ln*8;
  f32x4 acc0 = {0.f,0.f,0.f,0.f}, acc1 = {0.f,0.f,0.f,0.f};
  f32x4 acc2 = {0.f,0.f,0.f,0.f}, acc3 = {0.f,0.f,0.f,0.f};
#pragma unroll
  for (int kt = 0; kt < KT; ++kt) {
    short8v a = *reinterpret_cast<const short8v*>(aptr + kt*32);
    const unsigned short* bk = bptr + (size_t)kt*4*512;
    short8v b0 = *reinterpret_cast<const short8v*>(bk);
    short8v b1 = *reinterpret_cast<const short8v*>(bk + 512);
    short8v b2 = *reinterpret_cast<const short8v*>(bk + 1024);
    short8v b3 = *reinterpret_cast<const short8v*>(bk + 1536);
    acc0 = __builtin_amdgcn_mfma_f32_16x16x32_bf16(a, b0, acc0, 0, 0, 0);
    acc1 = __builtin_amdgcn_mfma_f32_16x16x32_bf16(a, b1, acc1, 0, 0, 0);
    acc2 = __builtin_amdgcn_mfma_f32_16x16x32_bf16(a, b2, acc2, 0, 0, 0);
    acc3 = __builtin_amdgcn_mfma_f32_16x16x32_bf16(a, b3, acc3, 0, 0, 0);
  }
  const int colc = ln & 15;
  const int rowe = rbase + ((ln >> 4) << 2);
  f32x4 av[4] = {acc0, acc1, acc2, acc3};
  float v[4][4];
#pragma unroll
  for (int i = 0; i < 4; ++i) {
    const int col = i*16 + colc;
    const float bs = bias[col];
#pragma unroll
    for (int r = 0; r < 4; ++r)
      v[i][r] = av[i][r] + bs + x[(size_t)(rowe + r)*64 + col];
  }
  float rs[4];
#pragma unroll
  for (int r = 0; r < 4; ++r) rs[r] = v[0][r]+v[1][r]+v[2][r]+v[3][r];
#pragma unroll
  for (int m = 1; m <= 8; m <<= 1)
#pragma unroll
    for (int r = 0; r < 4; ++r) rs[r] += __shfl_xor(rs[r], m, 64);
  float mean[4], vs[4];
#pragma unroll
  for (int r = 0; r < 4; ++r) { mean[r] = rs[r]*(1.0f/64.0f); vs[r] = 0.f; }
#pragma unroll
  for (int i = 0; i < 4; ++i)
#pragma unroll
    for (int r = 0; r < 4; ++r) { const float d = v[i][r]-mean[r]; vs[r] = fmaf(d, d, vs[r]); }
#pragma unroll
  for (int m = 1; m <= 8; m <<= 1)
#pragma unroll
    for (int r = 0; r < 4; ++r) vs[r] += __shfl_xor(vs[r], m, 64);
  float rstd[4];
#pragma unroll
  for (int r = 0; r < 4; ++r) rstd[r] = rsqrtf(vs[r]*(1.0f/64.0f) + 1e-5f);
#pragma unroll
  for (int i = 0; i < 4; ++i) {
    const int col = i*16 + colc;
    const float g = gam[col], bb = bet[col];
#pragma unroll
    for (int r = 0; r < 4; ++r) {
      const float out = (v[i][r]-mean[r])*rstd[r]*g + bb;
      x[(size_t)(rowe + r)*64 + col] = out;
      xbf[(size_t)(rowe + r)*64 + col] = f2bf(out);
    }
  }
}

// ---------------- MFMA GEMM + residual + LayerNorm fused (D=128 rows, gated) --
template<int K>
__global__ __launch_bounds__(256) void mgemm_ln128_kernel(
    const unsigned short* __restrict__ Abf,
    const unsigned short* __restrict__ Wpk,
    const float* __restrict__ bias,
    float* __restrict__ x,
    const float* __restrict__ gam, const float* __restrict__ bet,
    const int* __restrict__ nseg, unsigned short* __restrict__ xbf)
{
  constexpr int KT = K/32;
  const int row0 = blockIdx.x * 64;
  if ((row0 & (L_-1)) >= nseg[row0 >> 10]) return;
  const int wv = (int)threadIdx.x >> 6;
  const int ln = (int)threadIdx.x & 63;
  const int qc = ln & 15;
  const int rbase = row0 + wv*16;
  const unsigned short* aptr = Abf + (size_t)(rbase + qc)*K + ((ln >> 4) << 3);
  const unsigned short* bptr = Wpk + (size_t)ln*8;
  f32x4 acc[8];
#pragma unroll
  for (int i = 0; i < 8; ++i) acc[i] = f32x4{0.f,0.f,0.f,0.f};
#pragma unroll
  for (int kt = 0; kt < KT; ++kt) {
    short8v a = *reinterpret_cast<const short8v*>(aptr + kt*32);
    const unsigned short* bk = bptr + (size_t)kt*8*512;
#pragma unroll
    for (int i = 0; i < 8; ++i)
      acc[i] = __builtin_amdgcn_mfma_f32_16x16x32_bf16(
          a, *reinterpret_cast<const short8v*>(bk + i*512), acc[i], 0, 0, 0);
  }
  const int rowe = rbase + ((ln >> 4) << 2);
  float v[8][4];
#pragma unroll
  for (int i = 0; i < 8; ++i) {
    const int col = i*16 + qc;
    const float bs = bias[col];
#pragma unroll
    for (int r = 0; r < 4; ++r)
      v[i][r] = acc[i][r] + bs + x[(size_t)(rowe + r)*128 + col];
  }
  float rs[4];
#pragma unroll
  for (int r = 0; r < 4; ++r)
    rs[r] = ((v[0][r]+v[1][r])+(v[2][r]+v[3][r])) + ((v[4][r]+v[5][r])+(v[6][r]+v[7][r]));
#pragma unroll
  for (int m = 1; m <= 8; m <<= 1)
#pragma unroll
    for (int r = 0; r < 4; ++r) rs[r] += __shfl_xor(rs[r], m, 64);
  float mean[4], vs[4];
#pragma unroll
  for (int r = 0; r < 4; ++r) { mean[r] = rs[r]*(1.0f/128.0f); vs[r] = 0.f; }
#pragma unroll
  for (int i = 0; i < 8; ++i)
#pragma unroll
    for (int r = 0; r < 4; ++r) { const float d = v[i][r]-mean[r]; vs[r] = fmaf(d, d, vs[r]); }
#pragma unroll
  for (int m = 1; m <= 8; m <<= 1)
#pragma unroll
    for (int r = 0; r < 4; ++r) vs[r] += __shfl_xor(vs[r], m, 64);
  float rstd[4];
#pragma unroll
  for (int r = 0; r < 4; ++r) rstd[r] = rsqrtf(vs[r]*(1.0f/128.0f) + 1e-5f);
#pragma unroll
  for (int i = 0; i < 8; ++i) {
    const int col = i*16 + qc;
    const float g = gam[col], bb = bet[col];
#pragma unroll
    for (int r = 0; r < 4; ++r) {
      const float out = (v[i][r]-mean[r])*rstd[r]*g + bb;
      x[(size_t)(rowe + r)*128 + col] = out;
      xbf[(size_t)(rowe + r)*128 + col] = f2bf(out);
    }
  }
}

// ---------------- fused FF block (seg): FF1(relu) -> LDS -> FF2 + res + LN64 --
__global__ __launch_bounds__(256) void seg_ff_kernel(
    const unsigned short* __restrict__ Abf,   // zx_bf [M][64]
    const unsigned short* __restrict__ W1,    // packed K=64,N=128
    const float* __restrict__ b1,
    const unsigned short* __restrict__ W2,    // packed K=128,N=64
    const float* __restrict__ b2,
    float* __restrict__ x, const float* __restrict__ gam, const float* __restrict__ bet,
    unsigned short* __restrict__ xbf)
{
  __shared__ unsigned short HS[64][136];     // 17.4 KB, pad 8 shorts
  const int row0 = blockIdx.x * 64;
  const int wv = (int)threadIdx.x >> 6;
  const int ln = (int)threadIdx.x & 63;
  const int rbase = row0 + wv*16;
  // ---- FF1: 64 -> 128, relu ----
  {
    const unsigned short* aptr = Abf + (size_t)(rbase + (ln & 15))*64 + ((ln >> 4) << 3);
    const unsigned short* bptr = W1 + (size_t)ln*8;
    f32x4 acc[8];
#pragma unroll
    for (int i = 0; i < 8; ++i) acc[i] = f32x4{0.f,0.f,0.f,0.f};
#pragma unroll
    for (int kt = 0; kt < 2; ++kt) {
      short8v a = *reinterpret_cast<const short8v*>(aptr + kt*32);
      const unsigned short* bk = bptr + (size_t)kt*8*512;
#pragma unroll
      for (int i = 0; i < 8; ++i)
        acc[i] = __builtin_amdgcn_mfma_f32_16x16x32_bf16(
            a, *reinterpret_cast<const short8v*>(bk + i*512), acc[i], 0, 0, 0);
    }
    const int rl = wv*16 + ((ln >> 4) << 2);
#pragma unroll
    for (int i = 0; i < 8; ++i) {
      const int col = i*16 + (ln & 15);
      const float bs = b1[col];
#pragma unroll
      for (int r = 0; r < 4; ++r)
        HS[rl + r][col] = f2bf(fmaxf(acc[i][r] + bs, 0.f));
    }
  }
  __syncthreads();
  // ---- FF2: 128 -> 64, + residual + LN ----
  const int rowl = wv*16 + (ln & 15);
  f32x4 acc2[4];
#pragma unroll
  for (int i = 0; i < 4; ++i) acc2[i] = f32x4{0.f,0.f,0.f,0.f};
#pragma unroll
  for (int kt = 0; kt < 4; ++kt) {
    short8v a = *reinterpret_cast<const short8v*>(&HS[rowl][kt*32 + ((ln >> 4) << 3)]);
    const unsigned short* bk = W2 + (size_t)ln*8 + (size_t)kt*4*512;
#pragma unroll
    for (int i = 0; i < 4; ++i)
      acc2[i] = __builtin_amdgcn_mfma_f32_16x16x32_bf16(
          a, *reinterpret_cast<const short8v*>(bk + i*512), acc2[i], 0, 0, 0);
  }
  const int colc = ln & 15;
  const int rowe = rbase + ((ln >> 4) << 2);
  float v[4][4];
#pragma unroll
  for (int i = 0; i < 4; ++i) {
    const int col = i*16 + colc;
    const float bs = b2[col];
#pragma unroll
    for (int r = 0; r < 4; ++r)
      v[i][r] = acc2[i][r] + bs + x[(size_t)(rowe + r)*64 + col];
  }
  float rs[4];
#pragma unroll
  for (int r = 0; r < 4; ++r) rs[r] = v[0][r]+v[1][r]+v[2][r]+v[3][r];
#pragma unroll
  for (int m = 1; m <= 8; m <<= 1)
#pragma unroll
    for (int r = 0; r < 4; ++r) rs[r] += __shfl_xor(rs[r], m, 64);
  float mean[4], vs[4];
#pragma unroll
  for (int r = 0; r < 4; ++r) { mean[r] = rs[r]*(1.0f/64.0f); vs[r] = 0.f; }
#pragma unroll
  for (int i = 0; i < 4; ++i)
#pragma unroll
    for (int r = 0; r < 4; ++r) { const float d = v[i][r]-mean[r]; vs[r] = fmaf(d, d, vs[r]); }
#pragma unroll
  for (int m = 1; m <= 8; m <<= 1)
#pragma unroll
    for (int r = 0; r < 4; ++r) vs[r] += __shfl_xor(vs[r], m, 64);
  float rstd[4];
#pragma unroll
  for (int r = 0; r < 4; ++r) rstd[r] = rsqrtf(vs[r]*(1.0f/64.0f) + 1e-5f);
#pragma unroll
  for (int i = 0; i < 4; ++i) {
    const int col = i*16 + colc;
    const float g = gam[col], bb = bet[col];
#pragma unroll
    for (int r = 0; r < 4; ++r) {
      const float out = (v[i][r]-mean[r])*rstd[r]*g + bb;
      x[(size_t)(rowe + r)*64 + col] = out;
      xbf[(size_t)(rowe + r)*64 + col] = f2bf(out);
    }
  }
}

// ---------------- fused FF block (glb): FF1(relu) -> LDS -> FF2 + res + LN128 -
__global__ __launch_bounds__(256) void glb_ff_kernel(
    const unsigned short* __restrict__ Abf,   // xg_bf [M][128]
    const unsigned short* __restrict__ W1,    // packed K=128,N=256
    const float* __restrict__ b1,
    const unsigned short* __restrict__ W2,    // packed K=256,N=128
    const float* __restrict__ b2,
    float* __restrict__ x, const float* __restrict__ gam, const float* __restrict__ bet,
    const int* __restrict__ nseg, unsigned short* __restrict__ xbf)
{
  __shared__ unsigned short HS[64][264];     // 33.8 KB, pad 8 shorts
  const int row0 = blockIdx.x * 64;
  if ((row0 & (L_-1)) >= nseg[row0 >> 10]) return;
  const int wv = (int)threadIdx.x >> 6;
  const int ln = (int)threadIdx.x & 63;
  const int qc = ln & 15;
  const int rbase = row0 + wv*16;
  // ---- FF1: 128 -> 256, relu ----
  {
    const unsigned short* aptr = Abf + (size_t)(rbase + qc)*128 + ((ln >> 4) << 3);
    const unsigned short* bptr = W1 + (size_t)ln*8;
    f32x4 acc[16];
#pragma unroll
    for (int i = 0; i < 16; ++i) acc[i] = f32x4{0.f,0.f,0.f,0.f};
#pragma unroll
    for (int kt = 0; kt < 4; ++kt) {
      short8v a = *reinterpret_cast<const short8v*>(aptr + kt*32);
      const unsigned short* bk = bptr + (size_t)kt*16*512;
#pragma unroll
      for (int i = 0; i < 16; ++i)
        acc[i] = __builtin_amdgcn_mfma_f32_16x16x32_bf16(
            a, *reinterpret_cast<const short8v*>(bk + i*512), acc[i], 0, 0, 0);
    }
    const int rl = wv*16 + ((ln >> 4) << 2);
#pragma unroll
    for (int i = 0; i < 16; ++i) {
      const int col = i*16 + qc;
      const float bs = b1[col];
#pragma unroll
      for (int r = 0; r < 4; ++r)
        HS[rl + r][col] = f2bf(fmaxf(acc[i][r] + bs, 0.f));
    }
  }
  __syncthreads();
  // ---- FF2: 256 -> 128, + residual + LN ----
  const int rowl = wv*16 + qc;
  f32x4 acc2[8];
#pragma unroll
  for (int i = 0; i < 8; ++i) acc2[i] = f32x4{0.f,0.f,0.f,0.f};
#pragma unroll
  for (int kt = 0; kt < 8; ++kt) {
    short8v a = *reinterpret_cast<const short8v*>(&HS[rowl][kt*32 + ((ln >> 4) << 3)]);
    const unsigned short* bk = W2 + (size_t)ln*8 + (size_t)kt*8*512;
#pragma unroll
    for (int i = 0; i < 8; ++i)
      acc2[i] = __builtin_amdgcn_mfma_f32_16x16x32_bf16(
          a, *reinterpret_cast<const short8v*>(bk + i*512), acc2[i], 0, 0, 0);
  }
  const int rowe = rbase + ((ln >> 4) << 2);
  float v[8][4];
#pragma unroll
  for (int i = 0; i < 8; ++i) {
    const int col = i*16 + qc;
    const float bs = b2[col];
#pragma unroll
    for (int r = 0; r < 4; ++r)
      v[i][r] = acc2[i][r] + bs + x[(size_t)(rowe + r)*128 + col];
  }
  float rs[4];
#pragma unroll
  for (int r = 0; r < 4; ++r)
    rs[r] = ((v[0][r]+v[1][r])+(v[2][r]+v[3][r])) + ((v[4][r]+v[5][r])+(v[6][r]+v[7][r]));
#pragma unroll
  for (int m = 1; m <= 8; m <<= 1)
#pragma unroll
    for (int r = 0; r < 4; ++r) rs[r] += __shfl_xor(rs[r], m, 64);
  float mean[4], vs[4];
#pragma unroll
  for (int r = 0; r < 4; ++r) { mean[r] = rs[r]*(1.0f/128.0f); vs[r] = 0.f; }
#pragma unroll
  for (int i = 0; i < 8; ++i)
#pragma unroll
    for (int r = 0; r < 4; ++r) { const float d = v[i][r]-mean[r]; vs[r] = fmaf(d, d, vs[r]); }
#pragma unroll
  for (int m = 1; m <= 8; m <<= 1)
#pragma unroll
    for (int r = 0; r < 4; ++r) vs[r] += __shfl_xor(vs[r], m, 64);
  float rstd[4];
#pragma unroll
  for (int r = 0; r < 4; ++r) rstd[r] = rsqrtf(vs[r]*(1.0f/128.0f) + 1e-5f);
#pragma unroll
  for (int i = 0; i < 8; ++i) {
    const int col = i*16 + qc;
    const float g = gam[col], bb = bet[col];
#pragma unroll
    for (int r = 0; r < 4; ++r) {
      const float out = (v[i][r]-mean[r])*rstd[r]*g + bb;
      x[(size_t)(rowe + r)*128 + col] = out;
      xbf[(size_t)(rowe + r)*128 + col] = f2bf(out);
    }
  }
}

// ---------------- featurize: 4 points per 256-thr block (dual-write) ----------
__global__ __launch_bounds__(256) void featurize_kernel(
    const float* __restrict__ pts, const float* __restrict__ fs, const float* __restrict__ ft,
    const float* __restrict__ w_space, const float* __restrict__ b_space,
    const float* __restrict__ w_time, const float* __restrict__ b_time,
    const float* __restrict__ w_fout, const float* __restrict__ b_fout,
    const float* __restrict__ w_gate, const float* __restrict__ b_gate,
    float* __restrict__ z, unsigned short* __restrict__ zbf, int* __restrict__ boundary)
{
  const int sub = threadIdx.x >> 6;
  const int d   = threadIdx.x & 63;
  const int p   = blockIdx.x * 4 + sub;
  const float TWO_PI = 6.283185307179586f;
  __shared__ float feat[4][32];
  __shared__ float tfeat[4][16];
  __shared__ float g96[4][96];
  const float x = pts[p*3+0], y = pts[p*3+1], t = pts[p*3+2];
  if (d < 16) {
    float sp = (x*fs[d] + y*fs[16+d]) * TWO_PI;
    feat[sub][d]    = sinf(sp);
    feat[sub][16+d] = cosf(sp);
  } else if (d < 24) {
    int r = d - 16;
    float tp = t * ft[r] * TWO_PI;
    tfeat[sub][r]   = sinf(tp);
    tfeat[sub][8+r] = cosf(tp);
  }
  __syncthreads();
  float sf = b_space[d];
#pragma unroll
  for (int k2 = 0; k2 < 32; ++k2) sf = fmaf(feat[sub][k2], w_space[k2*64+d], sf);
  g96[sub][d] = sf;
  if (d < 32) {
    float tf = b_time[d];
#pragma unroll
    for (int k2 = 0; k2 < 16; ++k2) tf = fmaf(tfeat[sub][k2], w_time[k2*32+d], tf);
    g96[sub][64+d] = tf;
  }
  __syncthreads();
  float zv = b_fout[d];
#pragma unroll
  for (int k2 = 0; k2 < 96; ++k2) zv = fmaf(g96[sub][k2], w_fout[k2*64+d], zv);
  z[(size_t)p*64+d] = zv;
  zbf[(size_t)p*64+d] = f2bf(zv);
  float gv = wave_reduce_sum(zv * w_gate[d]);
  if (d == 0) {
    float logit = gv + b_gate[0];
    float gate = 1.0f / (1.0f + expf(-logit));
    int bnd = (gate > 0.5f) ? 1 : 0;
    if ((p & (L_-1)) == 0) bnd = 1;
    boundary[p] = bnd;
  }
}

// ---------------- scan: seg_id, seg_start, n_seg ----------------
__global__ __launch_bounds__(1024) void scan_kernel(const int* __restrict__ boundary,
    int* __restrict__ seg_id, int* __restrict__ seg_start, int* __restrict__ n_seg)
{
  __shared__ int sc[1024];
  const int b = blockIdx.x, l = threadIdx.x;
  const int v = boundary[b*L_ + l];
  sc[l] = v;
  __syncthreads();
  for (int off = 1; off < 1024; off <<= 1) {
    int add = (l >= off) ? sc[l - off] : 0;
    __syncthreads();
    sc[l] += add;
    __syncthreads();
  }
  const int sid = sc[l] - 1;
  seg_id[b*L_ + l] = sid;
  if (v) seg_start[b*(L_+1) + sid] = l;
  if (l == L_-1) {
    n_seg[b] = sid + 1;
    seg_start[b*(L_+1) + sid + 1] = L_;
  }
}

// ---------------- segment attention: 8 lanes per (pt,h) item -------------------
__global__ __launch_bounds__(256) void seg_attn_kernel(
    const float* __restrict__ qkv,
    const int* __restrict__ seg_id, const int* __restrict__ seg_start,
    unsigned short* __restrict__ aobf)
{
  const int gid = blockIdx.x * 256 + (int)threadIdx.x;  // item*8 + sub
  const int sub = gid & 7;
  const int item = gid >> 3;        // ((b*L + pt)*2 + h)
  const int h  = item & 1;
  const int pt = (item >> 1) & (L_-1);
  const int b  = item >> 11;
  const float scale = 0.17677669529663687f;
  float4 q4 = *reinterpret_cast<const float4*>(qkv + (size_t)(b*L_+pt)*192 + h*32 + sub*4);
  q4.x*=scale; q4.y*=scale; q4.z*=scale; q4.w*=scale;
  const int s  = seg_id[b*L_ + pt];
  const int j0 = seg_start[b*(L_+1) + s];
  const int j1 = seg_start[b*(L_+1) + s + 1];
  float lsum = 0.f;
  float4 acc = {0.f,0.f,0.f,0.f};
  for (int j = j0; j < j1; ++j) {
    const float* base = qkv + (size_t)(b*L_ + j)*192 + h*32 + sub*4;
    float4 k4 = *reinterpret_cast<const float4*>(base + 64);
    float4 v4 = *reinterpret_cast<const float4*>(base + 128);
    float dot = q4.x*k4.x;
    dot = fmaf(q4.y, k4.y, dot);
    dot = fmaf(q4.z, k4.z, dot);
    dot = fmaf(q4.w, k4.w, dot);
    dot += __shfl_xor(dot, 1, 64);
    dot += __shfl_xor(dot, 2, 64);
    dot += __shfl_xor(dot, 4, 64);
    const float p = __expf(fminf(dot, 30.f));
    lsum += p;
    acc.x = fmaf(p, v4.x, acc.x);
    acc.y = fmaf(p, v4.y, acc.y);
    acc.z = fmaf(p, v4.z, acc.z);
    acc.w = fmaf(p, v4.w, acc.w);
  }
  const float inv = 1.0f / lsum;
  unsigned* op = reinterpret_cast<unsigned*>(aobf + (size_t)(b*L_+pt)*64 + h*32 + sub*4);
  op[0] = (unsigned)f2bf(acc.x*inv) | ((unsigned)f2bf(acc.y*inv) << 16);
  op[1] = (unsigned)f2bf(acc.z*inv) | ((unsigned)f2bf(acc.w*inv) << 16);
}

// ---------------- global attention via MFMA (coalesced frags, XCD-swizzled) ----
__global__ __launch_bounds__(256) void glb_attn_mfma_kernel(
    const unsigned short* __restrict__ qbf,
    const unsigned short* __restrict__ kfrag,
    const unsigned short* __restrict__ vfrag,
    const int* __restrict__ n_seg,
    unsigned short* __restrict__ aobf)
{
  const int g64 = blockIdx.x & 63;    // (b*4 + h)
  const int qt  = blockIdx.x >> 6;
  const int h  = g64 & 3;
  const int b  = g64 >> 2;
  const int ns = n_seg[b];
  if (qt*64 >= ns) return;
  const int wv = (int)threadIdx.x >> 6;
  const int ln = (int)threadIdx.x & 63;
  const int g  = ln >> 4;
  const int qc = ln & 15;
  __shared__ float lsumS[4][16];

  const int q0 = qt*64 + wv*16;
  const short8v qf = *reinterpret_cast<const short8v*>(
      qbf + (size_t)(b*L_ + q0 + qc)*128 + h*32 + g*8);

  f32x4 O0 = {0.f,0.f,0.f,0.f}, O1 = {0.f,0.f,0.f,0.f};
  const f32x4 zz = {0.f,0.f,0.f,0.f};
  float lsum = 0.f;
  const unsigned short* kfb = kfrag + (size_t)((b*4 + h)*32)*1024 + (size_t)ln*8;
  const unsigned short* vfb = vfrag + (size_t)((b*4 + h)*32)*1024 + (size_t)ln*8;

  const int nfull = ns >> 5;
#pragma unroll 2
  for (int c = 0; c < nfull; ++c) {
    short8v kf0 = *reinterpret_cast<const short8v*>(kfb);
    short8v kf1 = *reinterpret_cast<const short8v*>(kfb + 512);
    short8v v0  = *reinterpret_cast<const short8v*>(vfb);
    short8v v1  = *reinterpret_cast<const short8v*>(vfb + 512);
    f32x4 s0 = __builtin_amdgcn_mfma_f32_16x16x32_bf16(kf0, qf, zz, 0, 0, 0);
    f32x4 s1 = __builtin_amdgcn_mfma_f32_16x16x32_bf16(kf1, qf, zz, 0, 0, 0);
    float p[8];
#pragma unroll
    for (int r = 0; r < 4; ++r) {
      const float e0 = exp2f(fminf(s0[r], 43.f));
      const float e1 = exp2f(fminf(s1[r], 43.f));
      p[r] = e0; p[4+r] = e1;
      lsum += e0 + e1;
    }
    short8v pf;
#pragma unroll
    for (int i = 0; i < 8; ++i) pf[i] = (short)f2bf(p[i]);
    O0 = __builtin_amdgcn_mfma_f32_16x16x32_bf16(pf, v0, O0, 0, 0, 0);
    O1 = __builtin_amdgcn_mfma_f32_16x16x32_bf16(pf, v1, O1, 0, 0, 0);
    kfb += 1024; vfb += 1024;
  }
  if (ns & 31) {
    short8v kf0 = *reinterpret_cast<const short8v*>(kfb);
    short8v kf1 = *reinterpret_cast<const short8v*>(kfb + 512);
    short8v v0  = *reinterpret_cast<const short8v*>(vfb);
    short8v v1  = *reinterpret_cast<const short8v*>(vfb + 512);
    f32x4 s0 = __builtin_amdgcn_mfma_f32_16x16x32_bf16(kf0, qf, zz, 0, 0, 0);
    f32x4 s1 = __builtin_amdgcn_mfma_f32_16x16x32_bf16(kf1, qf, zz, 0, 0, 0);
    const int k0 = nfull*32;
    float p[8];
#pragma unroll
    for (int r = 0; r < 4; ++r) {
      const int key0 = k0 + g*4 + r;
      const float e0 = (key0 < ns)      ? exp2f(fminf(s0[r], 43.f)) : 0.f;
      const float e1 = (key0 + 16 < ns) ? exp2f(fminf(s1[r], 43.f)) : 0.f;
      p[r] = e0; p[4+r] = e1;
      lsum += e0 + e1;
    }
    short8v pf;
#pragma unroll
    for (int i = 0; i < 8; ++i) pf[i] = (short)f2bf(p[i]);
    O0 = __builtin_amdgcn_mfma_f32_16x16x32_bf16(pf, v0, O0, 0, 0, 0);
    O1 = __builtin_amdgcn_mfma_f32_16x16x32_bf16(pf, v1, O1, 0, 0, 0);
  }
  lsum += __shfl_xor(lsum, 16, 64);
  lsum += __shfl_xor(lsum, 32, 64);
  if (ln < 16) lsumS[wv][ln] = lsum;
  __syncthreads();
  unsigned short* outp = aobf + (size_t)(b*L_ + q0 + g*4)*128 + h*32 + qc;
#pragma unroll
  for (int r = 0; r < 4; ++r) {
    const float inv = 1.0f / lsumS[wv][g*4 + r];
    outp[(size_t)r*128]      = f2bf(O0[r]*inv);
    outp[(size_t)r*128 + 16] = f2bf(O1[r]*inv);
  }
}

// ---------------- segment mean pooling -> bf16 [row][64] ----------------
__global__ __launch_bounds__(256) void pool_kernel(
    const float* __restrict__ h, const int* __restrict__ seg_start,
    const int* __restrict__ n_seg, unsigned short* __restrict__ meanbf)
{
  const int gs = blockIdx.x*4 + ((int)threadIdx.x >> 6);
  const int b = gs >> 10, s = gs & (L_-1);
  const int d = (int)threadIdx.x & 63;
  if (s >= n_seg[b]) return;
  const int j0 = seg_start[b*(L_+1)+s], j1 = seg_start[b*(L_+1)+s+1];
  float acc = 0.f;
  for (int j = j0; j < j1; ++j) acc += h[(size_t)(b*L_+j)*64 + d];
  meanbf[(size_t)gs*64 + d] = f2bf(acc / (float)(j1 - j0));
}

// ---------------- final: masked mean over valid rows + 128x128 projection ------
__global__ __launch_bounds__(1024) void final_kernel(
    const float* __restrict__ g, const float* __restrict__ semb0,
    const int* __restrict__ n_seg, const float* __restrict__ fin_w,
    const float* __restrict__ fin_b, float* __restrict__ out)
{
  const int b = blockIdx.x;
  const int ns = n_seg[b];
  const int d = (int)threadIdx.x & 127;
  const int c = (int)threadIdx.x >> 7;   // 0..7
  __shared__ float part[8][128];
  __shared__ float pl[128];
  float acc = 0.f;
  for (int i = c; i < ns; i += 8) acc += g[(size_t)(b*L_+i)*128 + d];
  part[c][d] = acc;
  __syncthreads();
  if (c == 0) {
    float s = part[0][d]+part[1][d]+part[2][d]+part[3][d]
            + part[4][d]+part[5][d]+part[6][d]+part[7][d];
    pl[d] = (ns == 1) ? semb0[b*128 + d] : s / (float)ns;
  }
  __syncthreads();
  if (c == 0) {
    float o = fin_b[d];
#pragma unroll 8
    for (int k2 = 0; k2 < 128; ++k2) o = fmaf(pl[k2], fin_w[k2*128+d], o);
    out[b*128+d] = o;
  }
}

extern "C" void kernel_launch(void* const* d_in, const int* in_sizes, int n_in,
                              void* d_out, int out_size, void* d_ws, size_t ws_size,
                              hipStream_t stream) {
  const float* pts     = (const float*)d_in[0];
  const float* fs      = (const float*)d_in[1];
  const float* ft      = (const float*)d_in[2];
  const float* w_space = (const float*)d_in[3];
  const float* b_space = (const float*)d_in[4];
  const float* w_time  = (const float*)d_in[5];
  const float* b_time  = (const float*)d_in[6];
  const float* w_fout  = (const float*)d_in[7];
  const float* b_fout  = (const float*)d_in[8];
  const float* w_gate  = (const float*)d_in[9];
  const float* b_gate  = (const float*)d_in[10];
  const float* seg_attn_w = (const float*)d_in[11];
  const float* seg_attn_b = (const float*)d_in[12];
  const float* seg_ln_g   = (const float*)d_in[13];
  const float* seg_ln_b   = (const float*)d_in[14];
  const float* seg_ff1_w  = (const float*)d_in[15];
  const float* seg_ff1_b  = (const float*)d_in[16];
  const float* seg_ff2_w  = (const float*)d_in[17];
  const float* seg_ff2_b  = (const float*)d_in[18];
  const float* glb_attn_w = (const float*)d_in[19];
  const float* glb_attn_b = (const float*)d_in[20];
  const float* glb_ln_g   = (const float*)d_in[21];
  const float* glb_ln_b   = (const float*)d_in[22];
  const float* glb_ff1_w  = (const float*)d_in[23];
  const float* glb_ff1_b  = (const float*)d_in[24];
  const float* glb_ff2_w  = (const float*)d_in[25];
  const float* glb_ff2_b  = (const float*)d_in[26];
  const float* up_w    = (const float*)d_in[27];
  const float* up_b    = (const float*)d_in[28];
  const float* fin_w   = (const float*)d_in[29];
  const float* fin_b   = (const float*)d_in[30];

  char* ws = (char*)d_ws;
  float* zx   = (float*)(ws);
  unsigned short* xg_bf = (unsigned short*)(ws);
  float* qkv  = (float*)(ws + ((size_t)4  << 20));   // seg fp32 qkv [16384][192]
  float* xg   = (float*)(ws + ((size_t)38 << 20));
  unsigned short* zx_bf = (unsigned short*)(ws + ((size_t)38 << 20));
  int* boundary  = (int*)(ws + ((size_t)46 << 20));
  int* seg_id    = boundary + M_TOT;
  int* seg_start = seg_id + M_TOT;
  int* n_seg     = seg_start + B_*(L_+1);
  float* semb0     = (float*)(ws + ((size_t)47 << 20));
  unsigned short* vfrag  = (unsigned short*)(ws + ((size_t)58 << 20));  // 4MB
  unsigned short* kfrag  = (unsigned short*)(ws + ((size_t)62 << 20));  // 4MB
  unsigned short* qbf    = (unsigned short*)(ws + ((size_t)66 << 20));  // 4MB
  unsigned short* abf    = (unsigned short*)(ws + ((size_t)84 << 20));
  unsigned short* wpk    = (unsigned short*)(ws + ((size_t)88 << 20));

  unsigned short* wpk_segA  = wpk;
  unsigned short* wpk_segF1 = wpk + 32768;
  unsigned short* wpk_segF2 = wpk + 49152;
  unsigned short* wpk_glbA  = wpk + 65536;
  unsigned short* wpk_glbF1 = wpk + 196608;
  unsigned short* wpk_glbF2 = wpk + 262144;
  unsigned short* wpk_up    = wpk + 327680;

  pack_all_kernel<<<164, 256, 0, stream>>>(seg_attn_w, seg_ff1_w, seg_ff2_w,
                                           glb_attn_w, glb_ff1_w, glb_ff2_w, up_w, wpk);

  featurize_kernel<<<M_TOT/4, 256, 0, stream>>>(pts, fs, ft, w_space, b_space, w_time, b_time,
                                                w_fout, b_fout, w_gate, b_gate, zx, zx_bf, boundary);
  scan_kernel<<<B_, 1024, 0, stream>>>(boundary, seg_id, seg_start, n_seg);

  // ---- segment-level encoder (D=64, H=2, FF=128); LN + FF fully fused ----
  for (int l = 0; l < 2; ++l) {
    const float* ab = seg_attn_b + (size_t)l*4*64;
    mgemm_kernel<64,64,3,false,false,true,false><<<dim3(256,3),256,0,stream>>>(
        zx_bf, wpk_segA + (size_t)l*4*4096, ab, qkv, nullptr, nullptr, nullptr);
    seg_attn_kernel<<<(M_TOT*2*8)/256, 256, 0, stream>>>(qkv, seg_id, seg_start, abf);
    mgemm_ln64_kernel<64><<<256,256,0,stream>>>(
        abf, wpk_segA + (size_t)(l*4+3)*4096, ab + 192,
        zx, seg_ln_g + l*128, seg_ln_b + l*128, zx_bf);
    seg_ff_kernel<<<256,256,0,stream>>>(
        zx_bf, wpk_segF1 + (size_t)l*8192, seg_ff1_b + l*128,
        wpk_segF2 + (size_t)l*8192, seg_ff2_b + l*64,
        zx, seg_ln_g + l*128 + 64, seg_ln_b + l*128 + 64, zx_bf);
  }

  // ---- pooling + up-projection (gated; semb0 snapshot fused) ----
  pool_kernel<<<M_TOT/4, 256, 0, stream>>>(zx, seg_start, n_seg, abf);
  mgemm_kernel<64,128,1,false,true,true,true,-1,true><<<dim3(256,2),256,0,stream>>>(
      abf, wpk_up, up_b, xg, xg_bf, n_seg, semb0);

  // ---- global-level encoder (D=128, H=4, FF=256), row-gated ----
  for (int l = 0; l < 2; ++l) {
    const float* ab = glb_attn_b + (size_t)l*4*128;
    mgemm_qkvfrag_kernel<<<dim3(256,6),256,0,stream>>>(
        xg_bf, wpk_glbA + (size_t)l*4*16384, ab, qbf, kfrag, vfrag, n_seg);
    glb_attn_mfma_kernel<<<B_*4*16, 256, 0, stream>>>(qbf, kfrag, vfrag, n_seg, abf);
    mgemm_ln128_kernel<128><<<256,256,0,stream>>>(
        abf, wpk_glbA + (size_t)(l*4+3)*16384, ab + 384,
        xg, glb_ln_g + l*256, glb_ln_b + l*256, n_seg, xg_bf);
    glb_ff_kernel<<<256,256,0,stream>>>(
        xg_bf, wpk_glbF1 + (size_t)l*32768, glb_ff1_b + l*256,
        wpk_glbF2 + (size_t)l*32768, glb_ff2_b + l*128,
        xg, glb_ln_g + l*256 + 128, glb_ln_b + l*256 + 128, n_seg, xg_bf);
  }

  final_kernel<<<B_, 1024, 0, stream>>>(xg, semb0, n_seg, fin_w, fin_b, (float*)d_out);
}